// Round 1
// baseline (502.579 us; speedup 1.0000x reference)
//
#include <hip/hip_runtime.h>
#include <hip/hip_bf16.h>

using bf16 = __hip_bfloat16;
typedef __attribute__((ext_vector_type(8))) short short8;
typedef __attribute__((ext_vector_type(4))) float f32x4;

#define DI __device__ __forceinline__

constexpr int MROWS = 16384;   // B * S
constexpr int EMB   = 1024;    // n_embd
constexpr int HID   = 4096;    // hidden

DI void gload16(const void* g, void* l) {
  __builtin_amdgcn_global_load_lds((const __attribute__((address_space(1))) void*)g,
                                   (__attribute__((address_space(3))) void*)l,
                                   16, 0, 0);
}

// scale = 2^(e-3), inv = 2^(3-e), e = floor(log2(amax)); clamp keeps both normal.
DI void qparams(float amax, float& scale, float& inv) {
  int eb = (int)((__float_as_uint(amax) >> 23) & 255u);
  eb = eb < 4 ? 4 : eb;
  scale = __uint_as_float((unsigned)(eb - 3) << 23);
  inv   = __uint_as_float((unsigned)(257 - eb) << 23);
}

// Block-quantize 32 f32 elements per thread -> bf16 (exact: 4 significand bits)
__global__ void quant32(const float* __restrict__ in, bf16* __restrict__ out, int nblk) {
  int b = blockIdx.x * blockDim.x + threadIdx.x;
  if (b >= nblk) return;
  const float4* p = (const float4*)(in + (size_t)b * 32);
  float4 v[8];
  float amax = 0.f;
#pragma unroll
  for (int i = 0; i < 8; i++) {
    v[i] = p[i];
    amax = fmaxf(amax, fmaxf(fmaxf(fabsf(v[i].x), fabsf(v[i].y)),
                             fmaxf(fabsf(v[i].z), fabsf(v[i].w))));
  }
  float scale, inv;
  qparams(amax, scale, inv);
  alignas(16) unsigned short us[32];
#pragma unroll
  for (int i = 0; i < 8; i++) {
    us[i * 4 + 0] = (unsigned short)(__float_as_uint(rintf(v[i].x * inv) * scale) >> 16);
    us[i * 4 + 1] = (unsigned short)(__float_as_uint(rintf(v[i].y * inv) * scale) >> 16);
    us[i * 4 + 2] = (unsigned short)(__float_as_uint(rintf(v[i].z * inv) * scale) >> 16);
    us[i * 4 + 3] = (unsigned short)(__float_as_uint(rintf(v[i].w * inv) * scale) >> 16);
  }
  short8* o = (short8*)(out + (size_t)b * 32);
#pragma unroll
  for (int i = 0; i < 4; i++) o[i] = *(short8*)(us + i * 8);
}

// C = A[M x Kd] * Bw[Nd x Kd]^T (both bf16, row-major, k-inner).
// GQ=true : epilogue adds bias, exact GELU, block-quant(32 along Nd), stores bf16.
// GQ=false: epilogue adds bias, stores f32.
template<int Kd, int Nd, bool GQ>
__global__ void __launch_bounds__(256)
gemm_bt(const bf16* __restrict__ A, const bf16* __restrict__ Bw,
        const float* __restrict__ bias, void* __restrict__ Cout) {
  __shared__ alignas(16) bf16 As[128 * 64];
  __shared__ alignas(16) bf16 Bs[128 * 64];
  const int tid  = threadIdx.x;
  const int wave = tid >> 6;
  const int lane = tid & 63;
  const int l16  = lane & 15;
  const int lhi  = lane >> 4;
  const int wr   = wave >> 1;   // 2x2 wave grid, each wave owns 64x64
  const int wc   = wave & 1;
  const int brow = blockIdx.y * 128;
  const int bcol = blockIdx.x * 128;

  f32x4 acc[4][4] = {};

  for (int kt = 0; kt < Kd; kt += 64) {
#pragma unroll
    for (int i = 0; i < 4; i++) {
      const int c   = i * 256 + tid;     // 16B chunk index within the 128x64 tile
      const int row = c >> 3;            // 8 chunks (64 bf16) per row
      const int k8  = (c & 7) * 8;
      gload16(A  + (size_t)(brow + row) * Kd + kt + k8,
              (char*)As + (size_t)(i * 256 + wave * 64) * 16);
      gload16(Bw + (size_t)(bcol + row) * Kd + kt + k8,
              (char*)Bs + (size_t)(i * 256 + wave * 64) * 16);
    }
    asm volatile("s_waitcnt vmcnt(0)" ::: "memory");
    __syncthreads();
#pragma unroll
    for (int kk = 0; kk < 2; kk++) {
      short8 af[4], bg[4];
#pragma unroll
      for (int m = 0; m < 4; m++)
        af[m] = *(const short8*)(const void*)(As + (wr * 64 + m * 16 + l16) * 64 + kk * 32 + lhi * 8);
#pragma unroll
      for (int n = 0; n < 4; n++)
        bg[n] = *(const short8*)(const void*)(Bs + (wc * 64 + n * 16 + l16) * 64 + kk * 32 + lhi * 8);
#pragma unroll
      for (int m = 0; m < 4; m++)
#pragma unroll
        for (int n = 0; n < 4; n++)
          acc[m][n] = __builtin_amdgcn_mfma_f32_16x16x32_bf16(af[m], bg[n], acc[m][n], 0, 0, 0);
    }
    __syncthreads();
  }

  const int colbase = bcol + wc * 64;
  float bias_v[4];
#pragma unroll
  for (int n = 0; n < 4; n++) bias_v[n] = bias[colbase + n * 16 + l16];

  if constexpr (GQ) {
    bf16* outp = (bf16*)Cout;
#pragma unroll
    for (int m = 0; m < 4; m++) {
      float g[4][4];
#pragma unroll
      for (int n = 0; n < 4; n++)
#pragma unroll
        for (int r = 0; r < 4; r++) {
          float v = acc[m][n][r] + bias_v[n];
          g[n][r] = 0.5f * v * (1.0f + erff(v * 0.70710678118654752f));
        }
      // quant blocks of 32 along Nd: frag pair (0,1) and (2,3); per row (=reg,lhi)
#pragma unroll
      for (int r = 0; r < 4; r++) {
        float a01 = fmaxf(fabsf(g[0][r]), fabsf(g[1][r]));
        float a23 = fmaxf(fabsf(g[2][r]), fabsf(g[3][r]));
#pragma unroll
        for (int msk = 1; msk <= 8; msk <<= 1) {
          a01 = fmaxf(a01, __shfl_xor(a01, msk, 64));
          a23 = fmaxf(a23, __shfl_xor(a23, msk, 64));
        }
        float s01, i01, s23, i23;
        qparams(a01, s01, i01);
        qparams(a23, s23, i23);
        const size_t rowoff = (size_t)(brow + wr * 64 + m * 16 + lhi * 4 + r) * Nd;
#pragma unroll
        for (int n = 0; n < 4; n++) {
          float sc = (n < 2) ? s01 : s23;
          float iv = (n < 2) ? i01 : i23;
          float q  = rintf(g[n][r] * iv) * sc;
          outp[rowoff + colbase + n * 16 + l16] = __float2bfloat16(q);
        }
      }
    }
  } else {
    float* outp = (float*)Cout;
#pragma unroll
    for (int m = 0; m < 4; m++)
#pragma unroll
      for (int n = 0; n < 4; n++)
#pragma unroll
        for (int r = 0; r < 4; r++) {
          const size_t rowoff = (size_t)(brow + wr * 64 + m * 16 + lhi * 4 + r) * Nd;
          outp[rowoff + colbase + n * 16 + l16] = acc[m][n][r] + bias_v[n];
        }
  }
}

extern "C" void kernel_launch(void* const* d_in, const int* in_sizes, int n_in,
                              void* d_out, int out_size, void* d_ws, size_t ws_size,
                              hipStream_t stream) {
  const float* x      = (const float*)d_in[0];
  const float* w_fc   = (const float*)d_in[1];
  const float* b_fc   = (const float*)d_in[2];
  const float* w_proj = (const float*)d_in[3];
  const float* b_proj = (const float*)d_in[4];

  char* ws = (char*)d_ws;
  bf16* xq  = (bf16*)ws;  ws += (size_t)MROWS * EMB * 2;   // 32 MB
  bf16* wfq = (bf16*)ws;  ws += (size_t)HID * EMB * 2;     //  8 MB
  bf16* wpq = (bf16*)ws;  ws += (size_t)EMB * HID * 2;     //  8 MB
  bf16* hq  = (bf16*)ws;                                   // 128 MB

  quant32<<<(MROWS * EMB / 32 + 255) / 256, 256, 0, stream>>>(x, xq, MROWS * EMB / 32);
  quant32<<<(HID * EMB / 32 + 255) / 256, 256, 0, stream>>>(w_fc, wfq, HID * EMB / 32);
  quant32<<<(EMB * HID / 32 + 255) / 256, 256, 0, stream>>>(w_proj, wpq, EMB * HID / 32);

  gemm_bt<EMB, HID, true ><<<dim3(HID / 128, MROWS / 128), 256, 0, stream>>>(xq, wfq, b_fc, hq);
  gemm_bt<HID, EMB, false><<<dim3(EMB / 128, MROWS / 128), 256, 0, stream>>>(hq, wpq, b_proj, (float*)d_out);
}

// Round 2
// 428.372 us; speedup vs baseline: 1.1732x; 1.1732x over previous
//
#include <hip/hip_runtime.h>
#include <hip/hip_bf16.h>

using bf16 = __hip_bfloat16;
typedef __attribute__((ext_vector_type(8))) short short8;
typedef __attribute__((ext_vector_type(4))) float f32x4;

#define DI __device__ __forceinline__

constexpr int MROWS = 16384;   // B * S
constexpr int EMB   = 1024;    // n_embd
constexpr int HID   = 4096;    // hidden

DI void gload16(const bf16* g, bf16* l) {
  __builtin_amdgcn_global_load_lds((const __attribute__((address_space(1))) void*)g,
                                   (__attribute__((address_space(3))) void*)l,
                                   16, 0, 0);
}

// scale = 2^(e-3), inv = 2^(3-e), e = floor(log2(amax)); clamp keeps both normal.
DI void qparams(float amax, float& scale, float& inv) {
  int eb = (int)((__float_as_uint(amax) >> 23) & 255u);
  eb = eb < 4 ? 4 : eb;
  scale = __uint_as_float((unsigned)(eb - 3) << 23);
  inv   = __uint_as_float((unsigned)(257 - eb) << 23);
}

// Block-quantize 32 f32 elements per thread -> bf16 (exact: 4 significand bits)
__global__ void quant32(const float* __restrict__ in, bf16* __restrict__ out, int nblk) {
  int b = blockIdx.x * blockDim.x + threadIdx.x;
  if (b >= nblk) return;
  const float4* p = (const float4*)(in + (size_t)b * 32);
  float4 v[8];
  float amax = 0.f;
#pragma unroll
  for (int i = 0; i < 8; i++) {
    v[i] = p[i];
    amax = fmaxf(amax, fmaxf(fmaxf(fabsf(v[i].x), fabsf(v[i].y)),
                             fmaxf(fabsf(v[i].z), fabsf(v[i].w))));
  }
  float scale, inv;
  qparams(amax, scale, inv);
  alignas(16) unsigned short us[32];
#pragma unroll
  for (int i = 0; i < 8; i++) {
    us[i * 4 + 0] = (unsigned short)(__float_as_uint(rintf(v[i].x * inv) * scale) >> 16);
    us[i * 4 + 1] = (unsigned short)(__float_as_uint(rintf(v[i].y * inv) * scale) >> 16);
    us[i * 4 + 2] = (unsigned short)(__float_as_uint(rintf(v[i].z * inv) * scale) >> 16);
    us[i * 4 + 3] = (unsigned short)(__float_as_uint(rintf(v[i].w * inv) * scale) >> 16);
  }
  short8* o = (short8*)(out + (size_t)b * 32);
#pragma unroll
  for (int i = 0; i < 4; i++) o[i] = *(short8*)(us + i * 8);
}

#define MFMA16(a, b, c) __builtin_amdgcn_mfma_f32_16x16x32_bf16(a, b, c, 0, 0, 0)
#define SBAR()   __builtin_amdgcn_s_barrier()
#define WAITLGKM0() asm volatile("s_waitcnt lgkmcnt(0)" ::: "memory")
#define WAITVM(n)   asm volatile("s_waitcnt vmcnt(" #n ")" ::: "memory")

// C = A[M x Kd] * Bw[Nd x Kd]^T, 256x256 tile, BK=64, 8 waves (2M x 4N),
// 8-phase schedule with counted vmcnt, XOR bank-swizzled LDS, setprio.
// Wave fragment interleave: A rows = m*32 + wr*16 + l16 (m=0..7),
//                           B rows = (n>>1)*128 + wc*32 + (n&1)*16 + l16 (n=0..3)
// so quadrant (mh,nh) touches exactly A-half mh / B-half nh for every wave,
// and each 32-col quant block of the GQ epilogue is wave-local.
template<int Kd, int Nd, bool GQ>
__global__ void __launch_bounds__(512, 2)
gemm8(const bf16* __restrict__ Ap, const bf16* __restrict__ Bp,
      const float* __restrict__ bias, void* __restrict__ Cout) {
  __shared__ bf16 Asm[2][2][128 * 64];
  __shared__ bf16 Bsm[2][2][128 * 64];

  const int tid  = threadIdx.x;
  const int lane = tid & 63, wave = tid >> 6;
  const int l16  = lane & 15, lhi = lane >> 4;
  const int wr   = wave >> 2, wc  = wave & 3;

  const int nbx = Nd / 256;
  const int nwg = gridDim.x;               // multiple of 8 here
  const int bid = blockIdx.x;
  const int swz = (bid & 7) * (nwg >> 3) + (bid >> 3);   // XCD-aware, bijective
  const int brow = (swz / nbx) * 256;
  const int bcol = (swz % nbx) * 256;

  // --- staging (global -> LDS, linear dest, inverse-swizzled source) ---
  const int r0 = tid >> 3;                  // row 0..63 (j=0), +64 for j=1
  const int sl = (tid & 7) ^ (r0 & 7);      // pre-swizzled 16B-slot in source row
  const bf16* asrc = Ap + (size_t)(brow + r0) * Kd + sl * 8;
  const bf16* bsrc = Bp + (size_t)(bcol + r0) * Kd + sl * 8;

  auto stageA = [&](int db, int half, int kt) {
    const bf16* s = asrc + (size_t)half * 128 * Kd + kt;
    bf16* d = &Asm[db][half][tid * 8];
    gload16(s, d);
    gload16(s + (size_t)64 * Kd, d + 4096);
  };
  auto stageB = [&](int db, int half, int kt) {
    const bf16* s = bsrc + (size_t)half * 128 * Kd + kt;
    bf16* d = &Bsm[db][half][tid * 8];
    gload16(s, d);
    gload16(s + (size_t)64 * Kd, d + 4096);
  };

  // --- fragment loads (swizzled ds_read_b128) ---
  const int sx = l16 & 7;                   // row&7 for all frag rows
  const int arow = wr * 16 + l16;           // + mi*32
  auto ldA = [&](int db, int mh, int mi, int kk) -> short8 {
    const int r = mi * 32 + arow;
    return *(const short8*)&Asm[db][mh][r * 64 + ((kk * 4 + lhi) ^ sx) * 8];
  };
  const int brl = wc * 32 + l16;            // + ni*16
  auto ldB = [&](int db, int half, int ni, int kk) -> short8 {
    const int r = brl + ni * 16;
    return *(const short8*)&Bsm[db][half][r * 64 + ((kk * 4 + lhi) ^ sx) * 8];
  };

  f32x4 acc[8][4] = {};
  short8 af[8], bgl[4], bgh[4];

  constexpr int NT = Kd / 64;

  // prologue: stage tile 0, order [A_lo, B_lo, B_hi, A_hi]
  stageA(0, 0, 0); stageB(0, 0, 0); stageB(0, 1, 0); stageA(0, 1, 0);
  WAITVM(4);                 // A_lo, B_lo landed; B_hi/A_hi still in flight
  SBAR();

  for (int t = 0; t < NT - 1; ++t) {
    const int db = t & 1, nb = db ^ 1, kt = (t + 1) * 64;
    // ---- q0: quadrant (mh=0, nh=0); stage A_lo(t+1)
    stageA(nb, 0, kt);
#pragma unroll
    for (int mi = 0; mi < 4; mi++) {
      af[mi * 2]     = ldA(db, 0, mi, 0);
      af[mi * 2 + 1] = ldA(db, 0, mi, 1);
    }
#pragma unroll
    for (int ni = 0; ni < 2; ni++) {
      bgl[ni * 2]     = ldB(db, 0, ni, 0);
      bgl[ni * 2 + 1] = ldB(db, 0, ni, 1);
    }
    SBAR(); WAITLGKM0();
    __builtin_amdgcn_s_setprio(1);
#pragma unroll
    for (int kk = 0; kk < 2; kk++)
#pragma unroll
      for (int mi = 0; mi < 4; mi++)
#pragma unroll
        for (int ni = 0; ni < 2; ni++)
          acc[mi][ni] = MFMA16(af[mi * 2 + kk], bgl[ni * 2 + kk], acc[mi][ni]);
    __builtin_amdgcn_s_setprio(0);
    WAITVM(4);               // B_hi(t) landed for q1's reads
    SBAR();
    // ---- q1: quadrant (mh=0, nh=1); stage B_lo(t+1)
    stageB(nb, 0, kt);
#pragma unroll
    for (int ni = 0; ni < 2; ni++) {
      bgh[ni * 2]     = ldB(db, 1, ni, 0);
      bgh[ni * 2 + 1] = ldB(db, 1, ni, 1);
    }
    SBAR(); WAITLGKM0();
    __builtin_amdgcn_s_setprio(1);
#pragma unroll
    for (int kk = 0; kk < 2; kk++)
#pragma unroll
      for (int mi = 0; mi < 4; mi++)
#pragma unroll
        for (int ni = 0; ni < 2; ni++)
          acc[mi][2 + ni] = MFMA16(af[mi * 2 + kk], bgh[ni * 2 + kk], acc[mi][2 + ni]);
    __builtin_amdgcn_s_setprio(0);
    WAITVM(4);               // A_hi(t) landed for q2's reads
    SBAR();
    // ---- q2: quadrant (mh=1, nh=0); stage B_hi(t+1)
    stageB(nb, 1, kt);
#pragma unroll
    for (int mi = 0; mi < 4; mi++) {
      af[mi * 2]     = ldA(db, 1, mi, 0);
      af[mi * 2 + 1] = ldA(db, 1, mi, 1);
    }
    SBAR(); WAITLGKM0();
    __builtin_amdgcn_s_setprio(1);
#pragma unroll
    for (int kk = 0; kk < 2; kk++)
#pragma unroll
      for (int mi = 0; mi < 4; mi++)
#pragma unroll
        for (int ni = 0; ni < 2; ni++)
          acc[4 + mi][ni] = MFMA16(af[mi * 2 + kk], bgl[ni * 2 + kk], acc[4 + mi][ni]);
    __builtin_amdgcn_s_setprio(0);
    SBAR();                  // no vmcnt needed
    // ---- q3: quadrant (mh=1, nh=1); stage A_hi(t+1)
    stageA(nb, 1, kt);
    SBAR();
    __builtin_amdgcn_s_setprio(1);
#pragma unroll
    for (int kk = 0; kk < 2; kk++)
#pragma unroll
      for (int mi = 0; mi < 4; mi++)
#pragma unroll
        for (int ni = 0; ni < 2; ni++)
          acc[4 + mi][2 + ni] = MFMA16(af[mi * 2 + kk], bgh[ni * 2 + kk], acc[4 + mi][2 + ni]);
    __builtin_amdgcn_s_setprio(0);
    WAITVM(4);               // A_lo(t+1), B_lo(t+1) landed for next q0
    SBAR();
  }

  // ---- tail tile t = NT-1 (no staging; drain 4 -> 2 -> 0)
  {
    const int db = (NT - 1) & 1;
#pragma unroll
    for (int mi = 0; mi < 4; mi++) {
      af[mi * 2]     = ldA(db, 0, mi, 0);
      af[mi * 2 + 1] = ldA(db, 0, mi, 1);
    }
#pragma unroll
    for (int ni = 0; ni < 2; ni++) {
      bgl[ni * 2]     = ldB(db, 0, ni, 0);
      bgl[ni * 2 + 1] = ldB(db, 0, ni, 1);
    }
    SBAR(); WAITLGKM0();
    __builtin_amdgcn_s_setprio(1);
#pragma unroll
    for (int kk = 0; kk < 2; kk++)
#pragma unroll
      for (int mi = 0; mi < 4; mi++)
#pragma unroll
        for (int ni = 0; ni < 2; ni++)
          acc[mi][ni] = MFMA16(af[mi * 2 + kk], bgl[ni * 2 + kk], acc[mi][ni]);
    __builtin_amdgcn_s_setprio(0);
    WAITVM(2);
    SBAR();
#pragma unroll
    for (int ni = 0; ni < 2; ni++) {
      bgh[ni * 2]     = ldB(db, 1, ni, 0);
      bgh[ni * 2 + 1] = ldB(db, 1, ni, 1);
    }
    SBAR(); WAITLGKM0();
    __builtin_amdgcn_s_setprio(1);
#pragma unroll
    for (int kk = 0; kk < 2; kk++)
#pragma unroll
      for (int mi = 0; mi < 4; mi++)
#pragma unroll
        for (int ni = 0; ni < 2; ni++)
          acc[mi][2 + ni] = MFMA16(af[mi * 2 + kk], bgh[ni * 2 + kk], acc[mi][2 + ni]);
    __builtin_amdgcn_s_setprio(0);
    WAITVM(0);
    SBAR();
#pragma unroll
    for (int mi = 0; mi < 4; mi++) {
      af[mi * 2]     = ldA(db, 1, mi, 0);
      af[mi * 2 + 1] = ldA(db, 1, mi, 1);
    }
    WAITLGKM0();
    __builtin_amdgcn_s_setprio(1);
#pragma unroll
    for (int kk = 0; kk < 2; kk++)
#pragma unroll
      for (int mi = 0; mi < 4; mi++)
#pragma unroll
        for (int ni = 0; ni < 2; ni++) {
          acc[4 + mi][ni]     = MFMA16(af[mi * 2 + kk], bgl[ni * 2 + kk], acc[4 + mi][ni]);
          acc[4 + mi][2 + ni] = MFMA16(af[mi * 2 + kk], bgh[ni * 2 + kk], acc[4 + mi][2 + ni]);
        }
    __builtin_amdgcn_s_setprio(0);
  }

  // ---- epilogue ----
  const int cb = bcol + wc * 32;
  float bv[4];
#pragma unroll
  for (int n = 0; n < 4; n++) bv[n] = bias[cb + (n >> 1) * 128 + (n & 1) * 16 + l16];

  if constexpr (GQ) {
    bf16* outp = (bf16*)Cout;
#pragma unroll
    for (int m = 0; m < 8; m++) {
      const size_t rbase = (size_t)(brow + m * 32 + wr * 16 + lhi * 4);
#pragma unroll
      for (int r = 0; r < 4; r++) {
        float g[4];
#pragma unroll
        for (int n = 0; n < 4; n++) {
          float v = acc[m][n][r] + bv[n];
          g[n] = 0.5f * v * (1.0f + erff(v * 0.70710678118654752f));
        }
#pragma unroll
        for (int p = 0; p < 2; p++) {
          float am = fmaxf(fabsf(g[p * 2]), fabsf(g[p * 2 + 1]));
#pragma unroll
          for (int msk = 1; msk <= 8; msk <<= 1) am = fmaxf(am, __shfl_xor(am, msk, 64));
          float sc, iv; qparams(am, sc, iv);
          const size_t ro = (rbase + r) * Nd + cb + p * 128;
          outp[ro + l16]      = __float2bfloat16(rintf(g[p * 2]     * iv) * sc);
          outp[ro + 16 + l16] = __float2bfloat16(rintf(g[p * 2 + 1] * iv) * sc);
        }
      }
    }
  } else {
    float* outp = (float*)Cout;
#pragma unroll
    for (int m = 0; m < 8; m++) {
      const size_t rbase = (size_t)(brow + m * 32 + wr * 16 + lhi * 4);
#pragma unroll
      for (int r = 0; r < 4; r++) {
        const size_t ro = (rbase + r) * Nd;
#pragma unroll
        for (int n = 0; n < 4; n++)
          outp[ro + cb + (n >> 1) * 128 + (n & 1) * 16 + l16] = acc[m][n][r] + bv[n];
      }
    }
  }
}

extern "C" void kernel_launch(void* const* d_in, const int* in_sizes, int n_in,
                              void* d_out, int out_size, void* d_ws, size_t ws_size,
                              hipStream_t stream) {
  const float* x      = (const float*)d_in[0];
  const float* w_fc   = (const float*)d_in[1];
  const float* b_fc   = (const float*)d_in[2];
  const float* w_proj = (const float*)d_in[3];
  const float* b_proj = (const float*)d_in[4];

  char* ws = (char*)d_ws;
  bf16* xq  = (bf16*)ws;  ws += (size_t)MROWS * EMB * 2;   // 32 MB
  bf16* wfq = (bf16*)ws;  ws += (size_t)HID * EMB * 2;     //  8 MB
  bf16* wpq = (bf16*)ws;  ws += (size_t)EMB * HID * 2;     //  8 MB
  bf16* hq  = (bf16*)ws;                                   // 128 MB

  quant32<<<(MROWS * EMB / 32 + 255) / 256, 256, 0, stream>>>(x, xq, MROWS * EMB / 32);
  quant32<<<(HID * EMB / 32 + 255) / 256, 256, 0, stream>>>(w_fc, wfq, HID * EMB / 32);
  quant32<<<(EMB * HID / 32 + 255) / 256, 256, 0, stream>>>(w_proj, wpq, EMB * HID / 32);

  gemm8<EMB, HID, true ><<<(MROWS / 256) * (HID / 256), 512, 0, stream>>>(xq, wfq, b_fc, hq);
  gemm8<HID, EMB, false><<<(MROWS / 256) * (EMB / 256), 512, 0, stream>>>(hq, wpq, b_proj, (float*)d_out);
}

// Round 3
// 357.566 us; speedup vs baseline: 1.4056x; 1.1980x over previous
//
#include <hip/hip_runtime.h>
#include <hip/hip_bf16.h>

using bf16 = __hip_bfloat16;
typedef __attribute__((ext_vector_type(8))) short short8;
typedef __attribute__((ext_vector_type(4))) float f32x4;

#define DI __device__ __forceinline__

constexpr int MROWS = 16384;   // B * S
constexpr int EMB   = 1024;    // n_embd
constexpr int HID   = 4096;    // hidden

DI void gload16(const bf16* g, bf16* l) {
  __builtin_amdgcn_global_load_lds((const __attribute__((address_space(1))) void*)g,
                                   (__attribute__((address_space(3))) void*)l,
                                   16, 0, 0);
}

// scale = 2^(e-3), inv = 2^(3-e), e = floor(log2(amax)); clamp keeps both normal.
DI void qparams(float amax, float& scale, float& inv) {
  int eb = (int)((__float_as_uint(amax) >> 23) & 255u);
  eb = eb < 4 ? 4 : eb;
  scale = __uint_as_float((unsigned)(eb - 3) << 23);
  inv   = __uint_as_float((unsigned)(257 - eb) << 23);
}

// Block-quantize 32 f32 elements per thread -> bf16 (exact: 4 significand bits)
__global__ void quant32(const float* __restrict__ in, bf16* __restrict__ out, int nblk) {
  int b = blockIdx.x * blockDim.x + threadIdx.x;
  if (b >= nblk) return;
  const float4* p = (const float4*)(in + (size_t)b * 32);
  float4 v[8];
  float amax = 0.f;
#pragma unroll
  for (int i = 0; i < 8; i++) {
    v[i] = p[i];
    amax = fmaxf(amax, fmaxf(fmaxf(fabsf(v[i].x), fabsf(v[i].y)),
                             fmaxf(fabsf(v[i].z), fabsf(v[i].w))));
  }
  float scale, inv;
  qparams(amax, scale, inv);
  alignas(16) unsigned short us[32];
#pragma unroll
  for (int i = 0; i < 8; i++) {
    us[i * 4 + 0] = (unsigned short)(__float_as_uint(rintf(v[i].x * inv) * scale) >> 16);
    us[i * 4 + 1] = (unsigned short)(__float_as_uint(rintf(v[i].y * inv) * scale) >> 16);
    us[i * 4 + 2] = (unsigned short)(__float_as_uint(rintf(v[i].z * inv) * scale) >> 16);
    us[i * 4 + 3] = (unsigned short)(__float_as_uint(rintf(v[i].w * inv) * scale) >> 16);
  }
  short8* o = (short8*)(out + (size_t)b * 32);
#pragma unroll
  for (int i = 0; i < 4; i++) o[i] = *(short8*)(us + i * 8);
}

#define MFMA16(a, b, c) __builtin_amdgcn_mfma_f32_16x16x32_bf16(a, b, c, 0, 0, 0)
#define SBAR()    __builtin_amdgcn_s_barrier()
#define WAITVM(n) asm volatile("s_waitcnt vmcnt(" #n ")" ::: "memory")

// Quadrant MFMA cluster (16 MFMA) wrapped in setprio
#define Q_MFMA(MB, NB, BG) \
  __builtin_amdgcn_s_setprio(1); \
  _Pragma("unroll") for (int kk = 0; kk < 2; kk++) \
  _Pragma("unroll") for (int mi = 0; mi < 4; mi++) \
  _Pragma("unroll") for (int ni = 0; ni < 2; ni++) \
    acc[(MB) + mi][(NB) + ni] = MFMA16(af[mi * 2 + kk], BG[ni * 2 + kk], acc[(MB) + mi][(NB) + ni]); \
  __builtin_amdgcn_s_setprio(0);

#define RD_A(mh) \
  _Pragma("unroll") for (int mi = 0; mi < 4; mi++) { \
    af[mi * 2]     = ldA(db, mh, mi, 0); \
    af[mi * 2 + 1] = ldA(db, mh, mi, 1); }

#define RD_B(half, dst) \
  _Pragma("unroll") for (int ni = 0; ni < 2; ni++) { \
    dst[ni * 2]     = ldB(db, half, ni, 0); \
    dst[ni * 2 + 1] = ldB(db, half, ni, 1); }

// C = A[M x Kd] * Bw[Nd x Kd]^T, 256x256 tile, BK=64, 8 waves (2M x 4N).
// m201-style schedule: 4 phases/K-tile, stage stream 3 phases ahead of use,
// ONE counted vmcnt(6) per K-tile (3 half-tiles in flight), XOR-swizzled LDS.
template<int Kd, int Nd, bool GQ>
__global__ void __launch_bounds__(512, 2)
gemm8(const bf16* __restrict__ Ap, const bf16* __restrict__ Bp,
      const float* __restrict__ bias, void* __restrict__ Cout) {
  __shared__ alignas(16) bf16 SH[65536];          // 128 KiB
  bf16* Abuf = SH;                                 // [2 dbuf][2 half][8192]
  bf16* Bbuf = SH + 32768;

  const int tid  = threadIdx.x;
  const int lane = tid & 63, wave = tid >> 6;
  const int l16  = lane & 15, lhi = lane >> 4;
  const int wr   = wave >> 2, wc  = wave & 3;

  // XCD-chunked, brow-fast ordering (rpc = 8 rows per XCD chunk)
  const int idx  = blockIdx.x >> 3;
  const int xid  = blockIdx.x & 7;
  const int brow = (xid * 8 + (idx & 7)) * 256;
  const int bcol = (idx >> 3) * 256;

  // staging: linear LDS dest, inverse-swizzled global source
  const int r0 = tid >> 3;
  const int sl = (tid & 7) ^ (r0 & 7);
  const bf16* asrc = Ap + (size_t)(brow + r0) * Kd + sl * 8;
  const bf16* bsrc = Bp + (size_t)(bcol + r0) * Kd + sl * 8;

  auto stA = [&](int tt, int half) {
    const bf16* s = asrc + (size_t)half * 128 * Kd + tt * 64;
    bf16* d = Abuf + ((tt & 1) * 2 + half) * 8192 + tid * 8;
    gload16(s, d); gload16(s + (size_t)64 * Kd, d + 4096);
  };
  auto stB = [&](int tt, int half) {
    const bf16* s = bsrc + (size_t)half * 128 * Kd + tt * 64;
    bf16* d = Bbuf + ((tt & 1) * 2 + half) * 8192 + tid * 8;
    gload16(s, d); gload16(s + (size_t)64 * Kd, d + 4096);
  };

  const int sx = l16 & 7;
  const int arow = wr * 16 + l16;
  auto ldA = [&](int db, int mh, int mi, int kk) -> short8 {
    return *(const short8*)(Abuf + (db * 2 + mh) * 8192 +
                            (mi * 32 + arow) * 64 + ((kk * 4 + lhi) ^ sx) * 8);
  };
  const int brl = wc * 32 + l16;
  auto ldB = [&](int db, int half, int ni, int kk) -> short8 {
    return *(const short8*)(Bbuf + (db * 2 + half) * 8192 +
                            (brl + ni * 16) * 64 + ((kk * 4 + lhi) ^ sx) * 8);
  };

  f32x4 acc[8][4] = {};
  short8 af[8], bgl[4], bgh[4];

  constexpr int NT = Kd / 64;                      // >= 3 for our shapes

  // prologue: tile 0 complete + first 3 half-tiles of tile 1
  stA(0, 0); stB(0, 0); stB(0, 1); stA(0, 1);
  stA(1, 0); stB(1, 0); stB(1, 1);
  WAITVM(6); SBAR();

  for (int t = 0; t <= NT - 3; ++t) {
    const int db = t & 1;
    // Phase A: stage A_hi(t+1); read A_lo frags + B_lo frags; MFMA q0
    stA(t + 1, 1);
    RD_A(0) RD_B(0, bgl)
    SBAR();
    Q_MFMA(0, 0, bgl)
    SBAR();
    // Phase B: stage A_lo(t+2); read B_hi frags; MFMA q1
    stA(t + 2, 0);
    RD_B(1, bgh)
    SBAR();
    Q_MFMA(0, 2, bgh)
    SBAR();
    // Phase C: stage B_lo(t+2); read A_hi frags; MFMA q2
    stB(t + 2, 0);
    RD_A(1)
    SBAR();
    Q_MFMA(4, 0, bgl)
    SBAR();
    // Phase D: stage B_hi(t+2); MFMA q3; single counted wait
    stB(t + 2, 1);
    Q_MFMA(4, 2, bgh)
    WAITVM(6); SBAR();
  }

  // peel t = NT-2: only A_hi(NT-1) left to stage; drain fully at D
  {
    const int db = (NT - 2) & 1;
    stA(NT - 1, 1);
    RD_A(0) RD_B(0, bgl)
    SBAR();
    Q_MFMA(0, 0, bgl)
    SBAR();
    RD_B(1, bgh)
    SBAR();
    Q_MFMA(0, 2, bgh)
    SBAR();
    RD_A(1)
    SBAR();
    Q_MFMA(4, 0, bgl)
    SBAR();
    Q_MFMA(4, 2, bgh)
    WAITVM(0); SBAR();
  }

  // tail t = NT-1: everything resident, straight-line, no barriers
  {
    const int db = (NT - 1) & 1;
    RD_A(0) RD_B(0, bgl)
    Q_MFMA(0, 0, bgl)
    RD_B(1, bgh)
    Q_MFMA(0, 2, bgh)
    RD_A(1)
    Q_MFMA(4, 0, bgl)
    Q_MFMA(4, 2, bgh)
  }

  // ---- epilogue ----
  const int cb = bcol + wc * 32;
  float bv[4];
#pragma unroll
  for (int n = 0; n < 4; n++) bv[n] = bias[cb + (n >> 1) * 128 + (n & 1) * 16 + l16];

  if constexpr (GQ) {
    SBAR();                                        // all tail LDS reads done
    // quantized bf16 C-tile staged in SH[256][256], then coalesced store
#pragma unroll
    for (int m = 0; m < 8; m++) {
      const int rl0 = m * 32 + wr * 16 + lhi * 4;
#pragma unroll
      for (int r = 0; r < 4; r++) {
        float g[4];
#pragma unroll
        for (int n = 0; n < 4; n++) {
          float v = acc[m][n][r] + bv[n];
          g[n] = 0.5f * v * (1.0f + erff(v * 0.70710678118654752f));
        }
#pragma unroll
        for (int p = 0; p < 2; p++) {
          float am = fmaxf(fabsf(g[p * 2]), fabsf(g[p * 2 + 1]));
#pragma unroll
          for (int msk = 1; msk <= 8; msk <<= 1) am = fmaxf(am, __shfl_xor(am, msk, 64));
          float sc, iv; qparams(am, sc, iv);
          const int co = (rl0 + r) * 256 + wc * 32 + p * 128 + l16;
          SH[co]      = __float2bfloat16(rintf(g[p * 2]     * iv) * sc);
          SH[co + 16] = __float2bfloat16(rintf(g[p * 2 + 1] * iv) * sc);
        }
      }
    }
    SBAR();
    bf16* outp = (bf16*)Cout;
#pragma unroll
    for (int i = 0; i < 16; i++) {
      const int c   = i * 512 + tid;               // 16B chunk id
      const int row = c >> 5, cc = c & 31;
      *(short8*)(outp + (size_t)(brow + row) * Nd + bcol + cc * 8) =
          *(const short8*)(SH + (size_t)c * 8);
    }
  } else {
    float* outp = (float*)Cout;
#pragma unroll
    for (int m = 0; m < 8; m++) {
      const size_t rbase = (size_t)(brow + m * 32 + wr * 16 + lhi * 4);
#pragma unroll
      for (int r = 0; r < 4; r++) {
        const size_t ro = (rbase + r) * Nd;
#pragma unroll
        for (int n = 0; n < 4; n++)
          outp[ro + cb + (n >> 1) * 128 + (n & 1) * 16 + l16] = acc[m][n][r] + bv[n];
      }
    }
  }
}

extern "C" void kernel_launch(void* const* d_in, const int* in_sizes, int n_in,
                              void* d_out, int out_size, void* d_ws, size_t ws_size,
                              hipStream_t stream) {
  const float* x      = (const float*)d_in[0];
  const float* w_fc   = (const float*)d_in[1];
  const float* b_fc   = (const float*)d_in[2];
  const float* w_proj = (const float*)d_in[3];
  const float* b_proj = (const float*)d_in[4];

  char* ws = (char*)d_ws;
  bf16* xq  = (bf16*)ws;  ws += (size_t)MROWS * EMB * 2;   // 32 MB
  bf16* wfq = (bf16*)ws;  ws += (size_t)HID * EMB * 2;     //  8 MB
  bf16* wpq = (bf16*)ws;  ws += (size_t)EMB * HID * 2;     //  8 MB
  bf16* hq  = (bf16*)ws;                                   // 128 MB

  quant32<<<(MROWS * EMB / 32 + 255) / 256, 256, 0, stream>>>(x, xq, MROWS * EMB / 32);
  quant32<<<(HID * EMB / 32 + 255) / 256, 256, 0, stream>>>(w_fc, wfq, HID * EMB / 32);
  quant32<<<(EMB * HID / 32 + 255) / 256, 256, 0, stream>>>(w_proj, wpq, EMB * HID / 32);

  gemm8<EMB, HID, true ><<<(MROWS / 256) * (HID / 256), 512, 0, stream>>>(xq, wfq, b_fc, hq);
  gemm8<HID, EMB, false><<<(MROWS / 256) * (EMB / 256), 512, 0, stream>>>(hq, wpq, b_proj, (float*)d_out);
}

// Round 4
// 344.933 us; speedup vs baseline: 1.4570x; 1.0366x over previous
//
#include <hip/hip_runtime.h>
#include <hip/hip_bf16.h>

using bf16 = __hip_bfloat16;
typedef __attribute__((ext_vector_type(8))) short short8;
typedef __attribute__((ext_vector_type(4))) float f32x4;

#define DI __device__ __forceinline__

constexpr int MROWS = 16384;   // B * S
constexpr int EMB   = 1024;    // n_embd
constexpr int HID   = 4096;    // hidden

DI void gload16(const bf16* g, bf16* l) {
  __builtin_amdgcn_global_load_lds((const __attribute__((address_space(1))) void*)g,
                                   (__attribute__((address_space(3))) void*)l,
                                   16, 0, 0);
}

// scale = 2^(e-3), inv = 2^(3-e), e = floor(log2(amax)); clamp keeps both normal.
DI void qparams(float amax, float& scale, float& inv) {
  int eb = (int)((__float_as_uint(amax) >> 23) & 255u);
  eb = eb < 4 ? 4 : eb;
  scale = __uint_as_float((unsigned)(eb - 3) << 23);
  inv   = __uint_as_float((unsigned)(257 - eb) << 23);
}

// Block-quantize 32 f32 elements per thread -> bf16 (exact: 4 significand bits)
__global__ void quant32(const float* __restrict__ in, bf16* __restrict__ out, int nblk) {
  int b = blockIdx.x * blockDim.x + threadIdx.x;
  if (b >= nblk) return;
  const float4* p = (const float4*)(in + (size_t)b * 32);
  float4 v[8];
  float amax = 0.f;
#pragma unroll
  for (int i = 0; i < 8; i++) {
    v[i] = p[i];
    amax = fmaxf(amax, fmaxf(fmaxf(fabsf(v[i].x), fabsf(v[i].y)),
                             fmaxf(fabsf(v[i].z), fabsf(v[i].w))));
  }
  float scale, inv;
  qparams(amax, scale, inv);
  alignas(16) unsigned short us[32];
#pragma unroll
  for (int i = 0; i < 8; i++) {
    us[i * 4 + 0] = (unsigned short)(__float_as_uint(rintf(v[i].x * inv) * scale) >> 16);
    us[i * 4 + 1] = (unsigned short)(__float_as_uint(rintf(v[i].y * inv) * scale) >> 16);
    us[i * 4 + 2] = (unsigned short)(__float_as_uint(rintf(v[i].z * inv) * scale) >> 16);
    us[i * 4 + 3] = (unsigned short)(__float_as_uint(rintf(v[i].w * inv) * scale) >> 16);
  }
  short8* o = (short8*)(out + (size_t)b * 32);
#pragma unroll
  for (int i = 0; i < 4; i++) o[i] = *(short8*)(us + i * 8);
}

#define MFMA16(a, b, c) __builtin_amdgcn_mfma_f32_16x16x32_bf16(a, b, c, 0, 0, 0)
#define SBAR()    __builtin_amdgcn_s_barrier()
#define WAITVM(n) asm volatile("s_waitcnt vmcnt(" #n ")" ::: "memory")

// Quadrant MFMA cluster (16 MFMA) wrapped in setprio
#define Q_MFMA(MB, NB, BG) \
  __builtin_amdgcn_s_setprio(1); \
  _Pragma("unroll") for (int kk = 0; kk < 2; kk++) \
  _Pragma("unroll") for (int mi = 0; mi < 4; mi++) \
  _Pragma("unroll") for (int ni = 0; ni < 2; ni++) \
    acc[(MB) + mi][(NB) + ni] = MFMA16(af[mi * 2 + kk], BG[ni * 2 + kk], acc[(MB) + mi][(NB) + ni]); \
  __builtin_amdgcn_s_setprio(0);

#define RD_AF(mh) \
  _Pragma("unroll") for (int mi = 0; mi < 4; mi++) { \
    af[mi * 2]     = ldA(db, mh, mi, 0); \
    af[mi * 2 + 1] = ldA(db, mh, mi, 1); }

#define RD_B(half, dst) \
  _Pragma("unroll") for (int ni = 0; ni < 2; ni++) { \
    dst[ni * 2]     = ldB(db, half, ni, 0); \
    dst[ni * 2 + 1] = ldB(db, half, ni, 1); }

// C = A[M x Kd] * Bw[Nd x Kd]^T, 256x256 tile, BK=64, 8 waves (2M x 4N).
// ONE barrier + ONE counted vmcnt(6) per K-tile; whole-tile fragment preload
// (A-frags reused lo->hi); stages threaded between MFMA quadrant clusters.
// Liveness: in-order DS completion + per-quadrant lgkm waits guarantee each
// staged overwrite target's reads have drained (A_lo(t+2) must-aliases the
// af_lo reads so program order is preserved by the compiler).
template<int Kd, int Nd, bool GQ>
__global__ void __launch_bounds__(512, 2)
gemm8(const bf16* __restrict__ Ap, const bf16* __restrict__ Bp,
      const float* __restrict__ bias, void* __restrict__ Cout) {
  __shared__ alignas(16) bf16 SH[65536];          // 128 KiB
  bf16* Abuf = SH;                                 // [2 dbuf][2 half][8192]
  bf16* Bbuf = SH + 32768;

  const int tid  = threadIdx.x;
  const int lane = tid & 63, wave = tid >> 6;
  const int l16  = lane & 15, lhi = lane >> 4;
  const int wr   = wave >> 2, wc  = wave & 3;

  // XCD-chunked, brow-fast ordering (8 brow per XCD chunk)
  const int idx  = blockIdx.x >> 3;
  const int xid  = blockIdx.x & 7;
  const int brow = (xid * 8 + (idx & 7)) * 256;
  const int bcol = (idx >> 3) * 256;

  // staging: linear LDS dest, inverse-swizzled global source
  const int r0 = tid >> 3;
  const int sl = (tid & 7) ^ (r0 & 7);
  const bf16* asrc = Ap + (size_t)(brow + r0) * Kd + sl * 8;
  const bf16* bsrc = Bp + (size_t)(bcol + r0) * Kd + sl * 8;

  auto stA = [&](int tt, int half) {
    const bf16* s = asrc + (size_t)half * 128 * Kd + tt * 64;
    bf16* d = Abuf + ((tt & 1) * 2 + half) * 8192 + tid * 8;
    gload16(s, d); gload16(s + (size_t)64 * Kd, d + 4096);
  };
  auto stB = [&](int tt, int half) {
    const bf16* s = bsrc + (size_t)half * 128 * Kd + tt * 64;
    bf16* d = Bbuf + ((tt & 1) * 2 + half) * 8192 + tid * 8;
    gload16(s, d); gload16(s + (size_t)64 * Kd, d + 4096);
  };

  const int sx = l16 & 7;
  const int arow = wr * 16 + l16;
  auto ldA = [&](int db, int mh, int mi, int kk) -> short8 {
    return *(const short8*)(Abuf + (db * 2 + mh) * 8192 +
                            (mi * 32 + arow) * 64 + ((kk * 4 + lhi) ^ sx) * 8);
  };
  const int brl = wc * 32 + l16;
  auto ldB = [&](int db, int half, int ni, int kk) -> short8 {
    return *(const short8*)(Bbuf + (db * 2 + half) * 8192 +
                            (brl + ni * 16) * 64 + ((kk * 4 + lhi) ^ sx) * 8);
  };

  f32x4 acc[8][4] = {};
  short8 af[8], bgl[4], bgh[4];

  constexpr int NT = Kd / 64;                      // >= 3 for our shapes

  // prologue: tile 0 complete (8 gloads) + {A_lo,B_lo,B_hi}(1) (6 gloads)
  stA(0, 0); stB(0, 0); stB(0, 1); stA(0, 1);
  stA(1, 0); stB(1, 0); stB(1, 1);
  WAITVM(6); SBAR();
  // invariant at tile top: buffer (t&1) fully staged; 6 in flight = {A_lo,B_lo,B_hi}(t+1)

  for (int t = 0; t <= NT - 3; ++t) {
    const int db = t & 1;
    RD_AF(0) RD_B(0, bgl) RD_B(1, bgh)    // reads 1-8 / 9-12 / 13-16 (in-order DS)
    stA(t + 1, 1);                         // -> A[nb][1], no conflict this tile
    Q_MFMA(0, 0, bgl)                      // waits reads 1-12
    stA(t + 2, 0);                         // overwrites A[db][0]: reads 1-8 drained
    Q_MFMA(0, 2, bgh)                      // waits reads 13-16
    stB(t + 2, 0);                         // overwrites B[db][0]: reads 9-12 drained
    RD_AF(1)                               // reads 17-24 (af regs reused)
    stB(t + 2, 1);                         // overwrites B[db][1]: reads 13-16 drained
    Q_MFMA(4, 0, bgl)                      // waits reads 17-24
    Q_MFMA(4, 2, bgh)
    WAITVM(6); SBAR();                     // drains 8 oldest -> tile t+1 resident
  }

  // peel t = NT-2: only A_hi(NT-1) remains to stage; drain fully
  {
    const int db = (NT - 2) & 1;
    RD_AF(0) RD_B(0, bgl) RD_B(1, bgh)
    stA(NT - 1, 1);
    Q_MFMA(0, 0, bgl)
    Q_MFMA(0, 2, bgh)
    RD_AF(1)
    Q_MFMA(4, 0, bgl)
    Q_MFMA(4, 2, bgh)
    WAITVM(0); SBAR();
  }

  // tail t = NT-1: everything resident
  {
    const int db = (NT - 1) & 1;
    RD_AF(0) RD_B(0, bgl) RD_B(1, bgh)
    Q_MFMA(0, 0, bgl)
    Q_MFMA(0, 2, bgh)
    RD_AF(1)
    Q_MFMA(4, 0, bgl)
    Q_MFMA(4, 2, bgh)
  }

  // ---- epilogue ----
  const int cb = bcol + wc * 32;
  float bv[4];
#pragma unroll
  for (int n = 0; n < 4; n++) bv[n] = bias[cb + (n >> 1) * 128 + (n & 1) * 16 + l16];

  if constexpr (GQ) {
    SBAR();                                // all tail LDS reads done (per-wave lgkm + barrier)
    // quantized bf16 C-tile staged in SH[256][256], cols XOR-swizzled by lhi<<3
#pragma unroll
    for (int m = 0; m < 8; m++) {
      const int rl0 = m * 32 + wr * 16 + lhi * 4;
#pragma unroll
      for (int r = 0; r < 4; r++) {
        float g[4];
#pragma unroll
        for (int n = 0; n < 4; n++) {
          float v = acc[m][n][r] + bv[n];
          g[n] = 0.5f * v * (1.0f + erff(v * 0.70710678118654752f));
        }
#pragma unroll
        for (int p = 0; p < 2; p++) {
          float am = fmaxf(fabsf(g[p * 2]), fabsf(g[p * 2 + 1]));
#pragma unroll
          for (int msk = 1; msk <= 8; msk <<= 1) am = fmaxf(am, __shfl_xor(am, msk, 64));
          float sc, iv; qparams(am, sc, iv);
          const int rowb = (rl0 + r) * 256;
          const int c0   = wc * 32 + p * 128;
          SH[rowb + ((c0 + l16)      ^ (lhi << 3))] = __float2bfloat16(rintf(g[p * 2]     * iv) * sc);
          SH[rowb + ((c0 + 16 + l16) ^ (lhi << 3))] = __float2bfloat16(rintf(g[p * 2 + 1] * iv) * sc);
        }
      }
    }
    SBAR();
    bf16* outp = (bf16*)Cout;
#pragma unroll
    for (int i = 0; i < 16; i++) {
      const int c   = i * 512 + tid;               // output 16B chunk id
      const int row = c >> 5, cc = c & 31;
      const int scc = cc ^ ((row >> 2) & 3);       // unswizzle chunk within row
      *(short8*)(outp + (size_t)(brow + row) * Nd + bcol + cc * 8) =
          *(const short8*)(SH + (size_t)row * 256 + scc * 8);
    }
  } else {
    float* outp = (float*)Cout;
#pragma unroll
    for (int m = 0; m < 8; m++) {
      const size_t rbase = (size_t)(brow + m * 32 + wr * 16 + lhi * 4);
#pragma unroll
      for (int r = 0; r < 4; r++) {
        const size_t ro = (rbase + r) * Nd;
#pragma unroll
        for (int n = 0; n < 4; n++)
          outp[ro + cb + (n >> 1) * 128 + (n & 1) * 16 + l16] = acc[m][n][r] + bv[n];
      }
    }
  }
}

extern "C" void kernel_launch(void* const* d_in, const int* in_sizes, int n_in,
                              void* d_out, int out_size, void* d_ws, size_t ws_size,
                              hipStream_t stream) {
  const float* x      = (const float*)d_in[0];
  const float* w_fc   = (const float*)d_in[1];
  const float* b_fc   = (const float*)d_in[2];
  const float* w_proj = (const float*)d_in[3];
  const float* b_proj = (const float*)d_in[4];

  char* ws = (char*)d_ws;
  bf16* xq  = (bf16*)ws;  ws += (size_t)MROWS * EMB * 2;   // 32 MB
  bf16* wfq = (bf16*)ws;  ws += (size_t)HID * EMB * 2;     //  8 MB
  bf16* wpq = (bf16*)ws;  ws += (size_t)EMB * HID * 2;     //  8 MB
  bf16* hq  = (bf16*)ws;                                   // 128 MB

  quant32<<<(MROWS * EMB / 32 + 255) / 256, 256, 0, stream>>>(x, xq, MROWS * EMB / 32);
  quant32<<<(HID * EMB / 32 + 255) / 256, 256, 0, stream>>>(w_fc, wfq, HID * EMB / 32);
  quant32<<<(EMB * HID / 32 + 255) / 256, 256, 0, stream>>>(w_proj, wpq, EMB * HID / 32);

  gemm8<EMB, HID, true ><<<(MROWS / 256) * (HID / 256), 512, 0, stream>>>(xq, wfq, b_fc, hq);
  gemm8<HID, EMB, false><<<(MROWS / 256) * (EMB / 256), 512, 0, stream>>>(hq, wpq, b_proj, (float*)d_out);
}